// Round 1
// baseline (357.139 us; speedup 1.0000x reference)
//
#include <hip/hip_runtime.h>
#include <hip/hip_bf16.h>

#define SEQ 2048
#define HID 3584
#define NQH 28
#define NKVH 4
#define HD 128
#define QKVN 4608
#define WIN 1024

typedef __bf16 bf16x8 __attribute__((ext_vector_type(8)));
typedef float f32x4 __attribute__((ext_vector_type(4)));
typedef unsigned int u32x4 __attribute__((ext_vector_type(4)));
typedef unsigned short u16x4 __attribute__((ext_vector_type(4)));

static __device__ __forceinline__ unsigned short f2bf(float f) {
  unsigned int u = __builtin_bit_cast(unsigned int, f);
  u += 0x7fffu + ((u >> 16) & 1u);
  return (unsigned short)(u >> 16);
}
static __device__ __forceinline__ float bf2f(unsigned short h) {
  unsigned int u = ((unsigned int)h) << 16;
  return __builtin_bit_cast(float, u);
}

// ---------- cast f32 -> bf16, 8 elems/thread ----------
__global__ __launch_bounds__(256) void k_cast8(const float* __restrict__ in,
                                               unsigned short* __restrict__ out, int n8) {
  int i = blockIdx.x * 256 + threadIdx.x;
  if (i >= n8) return;
  f32x4 a = ((const f32x4*)in)[2 * i];
  f32x4 b = ((const f32x4*)in)[2 * i + 1];
  union { unsigned short s[8]; u32x4 v; } u;
#pragma unroll
  for (int j = 0; j < 4; j++) { u.s[j] = f2bf(a[j]); u.s[4 + j] = f2bf(b[j]); }
  ((u32x4*)out)[i] = u.v;
}

// ---------- transpose + cast: out[c][r] = bf16(in[r][c]), R,C multiples of 64 ----------
__global__ __launch_bounds__(256) void k_tcast(const float* __restrict__ in,
                                               unsigned short* __restrict__ out, int R, int C) {
  __shared__ unsigned short tile[64][66];
  const int r0 = blockIdx.x * 64, c0 = blockIdx.y * 64;
  const int t = threadIdx.x;
  const int rg = t >> 4, cg = t & 15;
#pragma unroll
  for (int i = 0; i < 4; i++) {
    int rl = rg + i * 16;
    f32x4 v = *(const f32x4*)(in + (size_t)(r0 + rl) * C + c0 + cg * 4);
#pragma unroll
    for (int j = 0; j < 4; j++) tile[rl][cg * 4 + j] = f2bf(v[j]);
  }
  __syncthreads();
#pragma unroll
  for (int i = 0; i < 4; i++) {
    int cl = rg + i * 16;
    u16x4 o;
#pragma unroll
    for (int j = 0; j < 4; j++) o[j] = tile[cg * 4 + j][cl];
    *(u16x4*)(out + (size_t)(c0 + cl) * R + r0 + cg * 4) = o;
  }
}

// ---------- V transpose (bf16): vt[g*128+d][s] = qkv[s][4096 + g*128 + d] ----------
__global__ __launch_bounds__(256) void k_vtrans(const unsigned short* __restrict__ qkv,
                                                unsigned short* __restrict__ vt) {
  __shared__ unsigned short tile[64][66];
  const int r0 = blockIdx.x * 64;  // seq
  const int c0 = blockIdx.y * 64;  // g*128+d in [0,512)
  const int t = threadIdx.x;
  const int rg = t >> 4, cg = t & 15;
#pragma unroll
  for (int i = 0; i < 4; i++) {
    int rl = rg + i * 16;
    u16x4 v = *(const u16x4*)(qkv + (size_t)(r0 + rl) * QKVN + (NQH + NKVH) * HD + c0 + cg * 4);
#pragma unroll
    for (int j = 0; j < 4; j++) tile[rl][cg * 4 + j] = v[j];
  }
  __syncthreads();
#pragma unroll
  for (int i = 0; i < 4; i++) {
    int cl = rg + i * 16;
    u16x4 o;
#pragma unroll
    for (int j = 0; j < 4; j++) o[j] = tile[cg * 4 + j][cl];
    *(u16x4*)(vt + (size_t)(c0 + cl) * SEQ + r0 + cg * 4) = o;
  }
}

// ---------- RoPE in-place on q (heads 0..27) and k (heads 28..31) ----------
__global__ __launch_bounds__(256) void k_rope(unsigned short* __restrict__ qkv,
                                              const float* __restrict__ cosb,
                                              const float* __restrict__ sinb) {
  int idx = blockIdx.x * 256 + threadIdx.x;  // 2048*32*16 total
  int d4 = idx & 15;
  int head = (idx >> 4) & 31;
  int s = idx >> 9;
  unsigned short* row = qkv + (size_t)s * QKVN + head * HD;  // heads 0..31 are contiguous
  int d = d4 * 4;
  u16x4 x1v = *(u16x4*)(row + d);
  u16x4 x2v = *(u16x4*)(row + 64 + d);
  f32x4 c1 = *(const f32x4*)(cosb + s * HD + d);
  f32x4 s1 = *(const f32x4*)(sinb + s * HD + d);
  f32x4 c2 = *(const f32x4*)(cosb + s * HD + 64 + d);
  f32x4 s2 = *(const f32x4*)(sinb + s * HD + 64 + d);
  u16x4 o1, o2;
#pragma unroll
  for (int j = 0; j < 4; j++) {
    float x1 = bf2f(x1v[j]), x2 = bf2f(x2v[j]);
    o1[j] = f2bf(x1 * c1[j] - x2 * s1[j]);
    o2[j] = f2bf(x2 * c2[j] + x1 * s2[j]);
  }
  *(u16x4*)(row + d) = o1;
  *(u16x4*)(row + 64 + d) = o2;
}

// ---------- GEMM C[M][N] = A[M][K] * Bt[N][K]^T ; 128x128 tile, BK=64 ----------
// mode 0: C = bf16(A*B + bias)   mode 1: C = f32(A*B)
__global__ __launch_bounds__(256) void k_gemm_bt(const unsigned short* __restrict__ A,
                                                 const unsigned short* __restrict__ Bt,
                                                 const float* __restrict__ bias,
                                                 void* __restrict__ Cout,
                                                 int M, int N, int K, int mode) {
  __shared__ unsigned short Al[128 * 64];
  __shared__ unsigned short Bl[128 * 64];
  const int m0 = blockIdx.x * 128, n0 = blockIdx.y * 128;
  const int t = threadIdx.x;
  const int w = t >> 6, l = t & 63, lg = l >> 4, li = l & 15;
  const int wr = w >> 1, wc = w & 1;
  f32x4 acc[4][4] = {};
  const int nk = K >> 6;
  for (int kt = 0; kt < nk; kt++) {
    __syncthreads();
#pragma unroll
    for (int i = 0; i < 4; i++) {
      int s = t + i * 256;  // 0..1023 16B slots
      int row = s >> 3, sl = s & 7;
      int gofs = kt * 64 + sl * 8;
      u32x4 va = *(const u32x4*)(A + (size_t)(m0 + row) * K + gofs);
      u32x4 vb = *(const u32x4*)(Bt + (size_t)(n0 + row) * K + gofs);
      int lofs = row * 64 + ((sl ^ (row & 7)) * 8);
      *(u32x4*)(Al + lofs) = va;
      *(u32x4*)(Bl + lofs) = vb;
    }
    __syncthreads();
#pragma unroll
    for (int ks = 0; ks < 2; ks++) {
      bf16x8 af[4], bfr[4];
#pragma unroll
      for (int mi = 0; mi < 4; mi++) {
        int row = wr * 64 + mi * 16 + li;
        af[mi] = __builtin_bit_cast(
            bf16x8, *(const u32x4*)(Al + row * 64 + ((ks * 32 + lg * 8) ^ ((row & 7) << 3))));
      }
#pragma unroll
      for (int ni = 0; ni < 4; ni++) {
        int row = wc * 64 + ni * 16 + li;
        bfr[ni] = __builtin_bit_cast(
            bf16x8, *(const u32x4*)(Bl + row * 64 + ((ks * 32 + lg * 8) ^ ((row & 7) << 3))));
      }
#pragma unroll
      for (int mi = 0; mi < 4; mi++)
#pragma unroll
        for (int ni = 0; ni < 4; ni++)
          acc[mi][ni] = __builtin_amdgcn_mfma_f32_16x16x32_bf16(af[mi], bfr[ni], acc[mi][ni], 0, 0, 0);
    }
  }
  if (mode == 0) {
    float bv[4];
#pragma unroll
    for (int ni = 0; ni < 4; ni++) bv[ni] = bias[n0 + wc * 64 + ni * 16 + li];
    unsigned short* C16 = (unsigned short*)Cout;
#pragma unroll
    for (int mi = 0; mi < 4; mi++)
#pragma unroll
      for (int ni = 0; ni < 4; ni++)
#pragma unroll
        for (int r = 0; r < 4; r++) {
          int m = m0 + wr * 64 + mi * 16 + lg * 4 + r;
          int n = n0 + wc * 64 + ni * 16 + li;
          C16[(size_t)m * N + n] = f2bf(acc[mi][ni][r] + bv[ni]);
        }
  } else {
    float* Cf = (float*)Cout;
#pragma unroll
    for (int mi = 0; mi < 4; mi++)
#pragma unroll
      for (int ni = 0; ni < 4; ni++)
#pragma unroll
        for (int r = 0; r < 4; r++) {
          int m = m0 + wr * 64 + mi * 16 + lg * 4 + r;
          int n = n0 + wc * 64 + ni * 16 + li;
          Cf[(size_t)m * N + n] = acc[mi][ni][r];
        }
  }
}

// ---------- flash attention, sliding window, GQA ----------
// block = (qb, h): 64 q rows, head h (kv group h/7). 4 waves x 16 rows.
__global__ __launch_bounds__(256) void k_attn(const unsigned short* __restrict__ qkv,
                                              const unsigned short* __restrict__ vt,
                                              unsigned short* __restrict__ attnout) {
  __shared__ unsigned short Kl[64 * 128];
  __shared__ unsigned short Vl[128 * 64];
  __shared__ unsigned short Pl[4][16 * 64];

  const int qb = blockIdx.x;
  const int h = blockIdx.y;
  const int g = h / 7;
  const int t = threadIdx.x;
  const int w = t >> 6, l = t & 63, lg = l >> 4, li = l & 15;

  bf16x8 qf[4];
  {
    const int qrow = qb * 64 + w * 16 + li;
    const unsigned short* qp = qkv + (size_t)qrow * QKVN + h * HD;
#pragma unroll
    for (int ks = 0; ks < 4; ks++)
      qf[ks] = __builtin_bit_cast(bf16x8, *(const u32x4*)(qp + ks * 32 + lg * 8));
  }

  f32x4 oacc[8] = {};
  float mr[4], lr[4];
#pragma unroll
  for (int r = 0; r < 4; r++) { mr[r] = -1e30f; lr[r] = 0.f; }

  const int kt_lo = qb >= 16 ? qb - 16 : 0;
  const float scale = 0.088388347648318447f;  // 1/sqrt(128)

  for (int kt = kt_lo; kt <= qb; kt++) {
    __syncthreads();
    // stage K tile [64 keys][128 d], swizzled
#pragma unroll
    for (int i = 0; i < 4; i++) {
      int s = t + i * 256;
      int row = s >> 4, sl = s & 15;
      u32x4 v = *(const u32x4*)(qkv + (size_t)(kt * 64 + row) * QKVN + NQH * HD + g * HD + sl * 8);
      *(u32x4*)(Kl + row * 128 + ((sl ^ (row & 7)) * 8)) = v;
    }
    // stage V^T tile [128 d][64 keys], swizzled
#pragma unroll
    for (int i = 0; i < 4; i++) {
      int s = t + i * 256;
      int row = s >> 3, sl = s & 7;  // row = d
      u32x4 v = *(const u32x4*)(vt + (size_t)(g * HD + row) * SEQ + kt * 64 + sl * 8);
      *(u32x4*)(Vl + row * 64 + ((sl ^ (row & 7)) * 8)) = v;
    }
    __syncthreads();

    // S = Q K^T
    f32x4 sc[4] = {};
#pragma unroll
    for (int ks = 0; ks < 4; ks++) {
#pragma unroll
      for (int kb = 0; kb < 4; kb++) {
        int key = kb * 16 + li;
        int pos = (ks * 32 + lg * 8) ^ ((key & 7) << 3);
        bf16x8 kf = __builtin_bit_cast(bf16x8, *(const u32x4*)(Kl + key * 128 + pos));
        sc[kb] = __builtin_amdgcn_mfma_f32_16x16x32_bf16(qf[ks], kf, sc[kb], 0, 0, 0);
      }
    }

    // online softmax (rows partition by 16-lane group; reg r = row lg*4+r)
    float alpha[4];
#pragma unroll
    for (int r = 0; r < 4; r++) {
      int qg = qb * 64 + w * 16 + lg * 4 + r;
      float sv[4];
      float mx = -1e30f;
#pragma unroll
      for (int kb = 0; kb < 4; kb++) {
        int kg = kt * 64 + kb * 16 + li;
        float x = sc[kb][r] * scale;
        bool ok = (kg <= qg) && (qg - kg < WIN);
        sv[kb] = ok ? x : -1e30f;
        mx = fmaxf(mx, sv[kb]);
      }
#pragma unroll
      for (int off = 1; off < 16; off <<= 1) mx = fmaxf(mx, __shfl_xor(mx, off));
      float mn = fmaxf(mr[r], mx);
      alpha[r] = __expf(mr[r] - mn);
      float rs = 0.f;
      int q_l = lg * 4 + r;
#pragma unroll
      for (int kb = 0; kb < 4; kb++) {
        float p = (sv[kb] > -1e29f) ? __expf(sv[kb] - mn) : 0.f;
        rs += p;
        Pl[w][q_l * 64 + (((kb * 16 + li) ^ ((q_l & 7) << 3)))] = f2bf(p);
      }
#pragma unroll
      for (int off = 1; off < 16; off <<= 1) rs += __shfl_xor(rs, off);
      lr[r] = lr[r] * alpha[r] + rs;
      mr[r] = mn;
    }
#pragma unroll
    for (int db = 0; db < 8; db++)
#pragma unroll
      for (int r = 0; r < 4; r++) oacc[db][r] *= alpha[r];
    __syncthreads();  // P visible for A-fragment reads

    // O += P V
#pragma unroll
    for (int ks = 0; ks < 2; ks++) {
      int ppos = (ks * 32 + lg * 8) ^ ((li & 7) << 3);
      bf16x8 pf = __builtin_bit_cast(bf16x8, *(const u32x4*)(&Pl[w][li * 64 + ppos]));
#pragma unroll
      for (int db = 0; db < 8; db++) {
        int d = db * 16 + li;
        int vpos = (ks * 32 + lg * 8) ^ ((d & 7) << 3);
        bf16x8 vf = __builtin_bit_cast(bf16x8, *(const u32x4*)(Vl + d * 64 + vpos));
        oacc[db] = __builtin_amdgcn_mfma_f32_16x16x32_bf16(pf, vf, oacc[db], 0, 0, 0);
      }
    }
  }

#pragma unroll
  for (int r = 0; r < 4; r++) {
    float inv = 1.0f / lr[r];
    int qrow = qb * 64 + w * 16 + lg * 4 + r;
#pragma unroll
    for (int db = 0; db < 8; db++)
      attnout[(size_t)qrow * HID + h * HD + db * 16 + li] = f2bf(oacc[db][r] * inv);
  }
}

extern "C" void kernel_launch(void* const* d_in, const int* in_sizes, int n_in,
                              void* d_out, int out_size, void* d_ws, size_t ws_size,
                              hipStream_t stream) {
  const float* hidden = (const float*)d_in[0];
  const float* cosb = (const float*)d_in[1];
  const float* sinb = (const float*)d_in[2];
  const float* wqkv = (const float*)d_in[3];
  const float* bqkv = (const float*)d_in[4];
  const float* wo = (const float*)d_in[5];

  char* ws = (char*)d_ws;
  const size_t SZ_HBF = (size_t)SEQ * HID * 2;          // 14,680,064
  const size_t SZ_WQKVT = (size_t)QKVN * HID * 2;       // 33,030,144
  const size_t SZ_QKV = (size_t)SEQ * QKVN * 2;         // 18,874,368
  const size_t SZ_VT = (size_t)NKVH * HD * SEQ * 2;     // 2,097,152
  unsigned short* hbf = (unsigned short*)ws;
  unsigned short* wqkvT = (unsigned short*)(ws + SZ_HBF);
  unsigned short* qkv = (unsigned short*)(ws + SZ_HBF + SZ_WQKVT);
  unsigned short* vt = (unsigned short*)(ws + SZ_HBF + SZ_WQKVT + SZ_QKV);
  unsigned short* attn = (unsigned short*)(ws + SZ_HBF + SZ_WQKVT + SZ_QKV + SZ_VT);
  unsigned short* woT = wqkvT;  // reuse after QKV GEMM consumed wqkvT

  k_cast8<<<dim3(SEQ * HID / 8 / 256), 256, 0, stream>>>(hidden, hbf, SEQ * HID / 8);
  k_tcast<<<dim3(HID / 64, QKVN / 64), 256, 0, stream>>>(wqkv, wqkvT, HID, QKVN);
  k_gemm_bt<<<dim3(SEQ / 128, QKVN / 128), 256, 0, stream>>>(hbf, wqkvT, bqkv, qkv, SEQ, QKVN, HID, 0);
  k_rope<<<dim3(SEQ * 32 * 16 / 256), 256, 0, stream>>>(qkv, cosb, sinb);
  k_vtrans<<<dim3(SEQ / 64, (NKVH * HD) / 64), 256, 0, stream>>>(qkv, vt);
  k_tcast<<<dim3(HID / 64, HID / 64), 256, 0, stream>>>(wo, woT, HID, HID);
  k_attn<<<dim3(SEQ / 64, NQH), 256, 0, stream>>>(qkv, vt, attn);
  k_gemm_bt<<<dim3(SEQ / 128, HID / 128), 256, 0, stream>>>(attn, woT, nullptr, d_out, SEQ, HID, HID, 1);
}

// Round 2
// 351.393 us; speedup vs baseline: 1.0164x; 1.0164x over previous
//
#include <hip/hip_runtime.h>
#include <hip/hip_bf16.h>

#define SEQ 2048
#define HID 3584
#define NQH 28
#define NKVH 4
#define HD 128
#define QKVN 4608
#define WIN 1024

typedef __bf16 bf16x8 __attribute__((ext_vector_type(8)));
typedef float f32x4 __attribute__((ext_vector_type(4)));
typedef unsigned int u32x4 __attribute__((ext_vector_type(4)));
typedef unsigned short u16x4 __attribute__((ext_vector_type(4)));

static __device__ __forceinline__ unsigned short f2bf(float f) {
  unsigned int u = __builtin_bit_cast(unsigned int, f);
  u += 0x7fffu + ((u >> 16) & 1u);
  return (unsigned short)(u >> 16);
}
static __device__ __forceinline__ float bf2f(unsigned short h) {
  unsigned int u = ((unsigned int)h) << 16;
  return __builtin_bit_cast(float, u);
}

// async global->LDS, 16B per lane. lds base must be wave-uniform; HW adds lane*16.
static __device__ __forceinline__ void gload16(const unsigned short* g, unsigned short* l) {
  __builtin_amdgcn_global_load_lds(
      (const __attribute__((address_space(1))) unsigned int*)g,
      (__attribute__((address_space(3))) unsigned int*)l, 16, 0, 0);
}

// ---------- cast f32 -> bf16, 8 elems/thread ----------
__global__ __launch_bounds__(256) void k_cast8(const float* __restrict__ in,
                                               unsigned short* __restrict__ out, int n8) {
  int i = blockIdx.x * 256 + threadIdx.x;
  if (i >= n8) return;
  f32x4 a = ((const f32x4*)in)[2 * i];
  f32x4 b = ((const f32x4*)in)[2 * i + 1];
  union { unsigned short s[8]; u32x4 v; } u;
#pragma unroll
  for (int j = 0; j < 4; j++) { u.s[j] = f2bf(a[j]); u.s[4 + j] = f2bf(b[j]); }
  ((u32x4*)out)[i] = u.v;
}

// ---------- transpose + cast: out[c][r] = bf16(in[r][c]), R,C multiples of 64 ----------
__global__ __launch_bounds__(256) void k_tcast(const float* __restrict__ in,
                                               unsigned short* __restrict__ out, int R, int C) {
  __shared__ unsigned short tile[64][66];
  const int r0 = blockIdx.x * 64, c0 = blockIdx.y * 64;
  const int t = threadIdx.x;
  const int rg = t >> 4, cg = t & 15;
#pragma unroll
  for (int i = 0; i < 4; i++) {
    int rl = rg + i * 16;
    f32x4 v = *(const f32x4*)(in + (size_t)(r0 + rl) * C + c0 + cg * 4);
#pragma unroll
    for (int j = 0; j < 4; j++) tile[rl][cg * 4 + j] = f2bf(v[j]);
  }
  __syncthreads();
#pragma unroll
  for (int i = 0; i < 4; i++) {
    int cl = rg + i * 16;
    u16x4 o;
#pragma unroll
    for (int j = 0; j < 4; j++) o[j] = tile[cg * 4 + j][cl];
    *(u16x4*)(out + (size_t)(c0 + cl) * R + r0 + cg * 4) = o;
  }
}

// ---------- V transpose (bf16): vt[g*128+d][s] = qkv[s][4096 + g*128 + d] ----------
__global__ __launch_bounds__(256) void k_vtrans(const unsigned short* __restrict__ qkv,
                                                unsigned short* __restrict__ vt) {
  __shared__ unsigned short tile[64][66];
  const int r0 = blockIdx.x * 64;  // seq
  const int c0 = blockIdx.y * 64;  // g*128+d in [0,512)
  const int t = threadIdx.x;
  const int rg = t >> 4, cg = t & 15;
#pragma unroll
  for (int i = 0; i < 4; i++) {
    int rl = rg + i * 16;
    u16x4 v = *(const u16x4*)(qkv + (size_t)(r0 + rl) * QKVN + (NQH + NKVH) * HD + c0 + cg * 4);
#pragma unroll
    for (int j = 0; j < 4; j++) tile[rl][cg * 4 + j] = v[j];
  }
  __syncthreads();
#pragma unroll
  for (int i = 0; i < 4; i++) {
    int cl = rg + i * 16;
    u16x4 o;
#pragma unroll
    for (int j = 0; j < 4; j++) o[j] = tile[cg * 4 + j][cl];
    *(u16x4*)(vt + (size_t)(c0 + cl) * SEQ + r0 + cg * 4) = o;
  }
}

// ---------- RoPE in-place on q (heads 0..27) and k (heads 28..31) ----------
__global__ __launch_bounds__(256) void k_rope(unsigned short* __restrict__ qkv,
                                              const float* __restrict__ cosb,
                                              const float* __restrict__ sinb) {
  int idx = blockIdx.x * 256 + threadIdx.x;  // 2048*32*16 total
  int d4 = idx & 15;
  int head = (idx >> 4) & 31;
  int s = idx >> 9;
  unsigned short* row = qkv + (size_t)s * QKVN + head * HD;  // heads 0..31 are contiguous
  int d = d4 * 4;
  u16x4 x1v = *(u16x4*)(row + d);
  u16x4 x2v = *(u16x4*)(row + 64 + d);
  f32x4 c1 = *(const f32x4*)(cosb + s * HD + d);
  f32x4 s1 = *(const f32x4*)(sinb + s * HD + d);
  f32x4 c2 = *(const f32x4*)(cosb + s * HD + 64 + d);
  f32x4 s2 = *(const f32x4*)(sinb + s * HD + 64 + d);
  u16x4 o1, o2;
#pragma unroll
  for (int j = 0; j < 4; j++) {
    float x1 = bf2f(x1v[j]), x2 = bf2f(x2v[j]);
    o1[j] = f2bf(x1 * c1[j] - x2 * s1[j]);
    o2[j] = f2bf(x2 * c2[j] + x1 * s2[j]);
  }
  *(u16x4*)(row + d) = o1;
  *(u16x4*)(row + 64 + d) = o2;
}

// ---------- GEMM C[M][N] = A[M][K] * Bt[N][K]^T ; 128x128 tile, BK=64 ----------
// Staging via global_load_lds (linear LDS dest, inverse-swizzled global source;
// reads apply the same XOR involution -> conflict-free ds_read_b128).
// mode 0: C = bf16(A*B + bias)   mode 1: C = f32(A*B)
__global__ __launch_bounds__(256) void k_gemm_bt(const unsigned short* __restrict__ A,
                                                 const unsigned short* __restrict__ Bt,
                                                 const float* __restrict__ bias,
                                                 void* __restrict__ Cout,
                                                 int M, int N, int K, int mode) {
  __shared__ unsigned short Al[128 * 64];
  __shared__ unsigned short Bl[128 * 64];
  const int m0 = blockIdx.x * 128, n0 = blockIdx.y * 128;
  const int t = threadIdx.x;
  const int w = t >> 6, l = t & 63, lg = l >> 4, li = l & 15;
  const int wr = w >> 1, wc = w & 1;
  f32x4 acc[4][4] = {};
  const int nk = K >> 6;
  for (int kt = 0; kt < nk; kt++) {
    __syncthreads();
#pragma unroll
    for (int i = 0; i < 4; i++) {
      int sbase = i * 256 + w * 64;        // wave-uniform slot base (16B slots)
      int s = sbase + l;                   // this lane's slot
      int row = s >> 3, sl = s & 7;
      int slsrc = sl ^ (row & 7);          // inverse swizzle on the SOURCE
      const unsigned short* ga = A + (size_t)(m0 + row) * K + kt * 64 + slsrc * 8;
      const unsigned short* gb = Bt + (size_t)(n0 + row) * K + kt * 64 + slsrc * 8;
      gload16(ga, Al + sbase * 8);
      gload16(gb, Bl + sbase * 8);
    }
    __syncthreads();
#pragma unroll
    for (int ks = 0; ks < 2; ks++) {
      bf16x8 af[4], bfr[4];
#pragma unroll
      for (int mi = 0; mi < 4; mi++) {
        int row = wr * 64 + mi * 16 + li;
        af[mi] = __builtin_bit_cast(
            bf16x8, *(const u32x4*)(Al + row * 64 + ((ks * 32 + lg * 8) ^ ((row & 7) << 3))));
      }
#pragma unroll
      for (int ni = 0; ni < 4; ni++) {
        int row = wc * 64 + ni * 16 + li;
        bfr[ni] = __builtin_bit_cast(
            bf16x8, *(const u32x4*)(Bl + row * 64 + ((ks * 32 + lg * 8) ^ ((row & 7) << 3))));
      }
#pragma unroll
      for (int mi = 0; mi < 4; mi++)
#pragma unroll
        for (int ni = 0; ni < 4; ni++)
          acc[mi][ni] = __builtin_amdgcn_mfma_f32_16x16x32_bf16(af[mi], bfr[ni], acc[mi][ni], 0, 0, 0);
    }
  }
  if (mode == 0) {
    float bv[4];
#pragma unroll
    for (int ni = 0; ni < 4; ni++) bv[ni] = bias[n0 + wc * 64 + ni * 16 + li];
    unsigned short* C16 = (unsigned short*)Cout;
#pragma unroll
    for (int mi = 0; mi < 4; mi++)
#pragma unroll
      for (int ni = 0; ni < 4; ni++)
#pragma unroll
        for (int r = 0; r < 4; r++) {
          int m = m0 + wr * 64 + mi * 16 + lg * 4 + r;
          int n = n0 + wc * 64 + ni * 16 + li;
          C16[(size_t)m * N + n] = f2bf(acc[mi][ni][r] + bv[ni]);
        }
  } else {
    float* Cf = (float*)Cout;
#pragma unroll
    for (int mi = 0; mi < 4; mi++)
#pragma unroll
      for (int ni = 0; ni < 4; ni++)
#pragma unroll
        for (int r = 0; r < 4; r++) {
          int m = m0 + wr * 64 + mi * 16 + lg * 4 + r;
          int n = n0 + wc * 64 + ni * 16 + li;
          Cf[(size_t)m * N + n] = acc[mi][ni][r];
        }
  }
}

// ---------- flash attention, sliding window, GQA ----------
// block = (qb, h): 64 q rows, head h (kv group h/7). 4 waves x 16 rows.
__global__ __launch_bounds__(256) void k_attn(const unsigned short* __restrict__ qkv,
                                              const unsigned short* __restrict__ vt,
                                              unsigned short* __restrict__ attnout) {
  __shared__ unsigned short Kl[64 * 128];
  __shared__ unsigned short Vl[128 * 64];
  __shared__ unsigned short Pl[4][16 * 64];

  const int qb = blockIdx.x;
  const int h = blockIdx.y;
  const int g = h / 7;
  const int t = threadIdx.x;
  const int w = t >> 6, l = t & 63, lg = l >> 4, li = l & 15;

  bf16x8 qf[4];
  {
    const int qrow = qb * 64 + w * 16 + li;
    const unsigned short* qp = qkv + (size_t)qrow * QKVN + h * HD;
#pragma unroll
    for (int ks = 0; ks < 4; ks++)
      qf[ks] = __builtin_bit_cast(bf16x8, *(const u32x4*)(qp + ks * 32 + lg * 8));
  }

  f32x4 oacc[8] = {};
  float mr[4], lr[4];
#pragma unroll
  for (int r = 0; r < 4; r++) { mr[r] = -1e30f; lr[r] = 0.f; }

  const int kt_lo = qb >= 16 ? qb - 16 : 0;
  const float scale = 0.088388347648318447f;  // 1/sqrt(128)

  for (int kt = kt_lo; kt <= qb; kt++) {
    __syncthreads();
    // stage K tile [64 keys][128 d], swizzled
#pragma unroll
    for (int i = 0; i < 4; i++) {
      int s = t + i * 256;
      int row = s >> 4, sl = s & 15;
      u32x4 v = *(const u32x4*)(qkv + (size_t)(kt * 64 + row) * QKVN + NQH * HD + g * HD + sl * 8);
      *(u32x4*)(Kl + row * 128 + ((sl ^ (row & 7)) * 8)) = v;
    }
    // stage V^T tile [128 d][64 keys], swizzled
#pragma unroll
    for (int i = 0; i < 4; i++) {
      int s = t + i * 256;
      int row = s >> 3, sl = s & 7;  // row = d
      u32x4 v = *(const u32x4*)(vt + (size_t)(g * HD + row) * SEQ + kt * 64 + sl * 8);
      *(u32x4*)(Vl + row * 64 + ((sl ^ (row & 7)) * 8)) = v;
    }
    __syncthreads();

    // S = Q K^T
    f32x4 sc[4] = {};
#pragma unroll
    for (int ks = 0; ks < 4; ks++) {
#pragma unroll
      for (int kb = 0; kb < 4; kb++) {
        int key = kb * 16 + li;
        int pos = (ks * 32 + lg * 8) ^ ((key & 7) << 3);
        bf16x8 kf = __builtin_bit_cast(bf16x8, *(const u32x4*)(Kl + key * 128 + pos));
        sc[kb] = __builtin_amdgcn_mfma_f32_16x16x32_bf16(qf[ks], kf, sc[kb], 0, 0, 0);
      }
    }

    // online softmax (rows partition by 16-lane group; reg r = row lg*4+r)
    float alpha[4];
#pragma unroll
    for (int r = 0; r < 4; r++) {
      int qg = qb * 64 + w * 16 + lg * 4 + r;
      float sv[4];
      float mx = -1e30f;
#pragma unroll
      for (int kb = 0; kb < 4; kb++) {
        int kg = kt * 64 + kb * 16 + li;
        float x = sc[kb][r] * scale;
        bool ok = (kg <= qg) && (qg - kg < WIN);
        sv[kb] = ok ? x : -1e30f;
        mx = fmaxf(mx, sv[kb]);
      }
#pragma unroll
      for (int off = 1; off < 16; off <<= 1) mx = fmaxf(mx, __shfl_xor(mx, off));
      float mn = fmaxf(mr[r], mx);
      alpha[r] = __expf(mr[r] - mn);
      float rs = 0.f;
      int q_l = lg * 4 + r;
#pragma unroll
      for (int kb = 0; kb < 4; kb++) {
        float p = (sv[kb] > -1e29f) ? __expf(sv[kb] - mn) : 0.f;
        rs += p;
        Pl[w][q_l * 64 + (((kb * 16 + li) ^ ((q_l & 7) << 3)))] = f2bf(p);
      }
#pragma unroll
      for (int off = 1; off < 16; off <<= 1) rs += __shfl_xor(rs, off);
      lr[r] = lr[r] * alpha[r] + rs;
      mr[r] = mn;
    }
#pragma unroll
    for (int db = 0; db < 8; db++)
#pragma unroll
      for (int r = 0; r < 4; r++) oacc[db][r] *= alpha[r];
    __syncthreads();  // P visible for A-fragment reads

    // O += P V
#pragma unroll
    for (int ks = 0; ks < 2; ks++) {
      int ppos = (ks * 32 + lg * 8) ^ ((li & 7) << 3);
      bf16x8 pf = __builtin_bit_cast(bf16x8, *(const u32x4*)(&Pl[w][li * 64 + ppos]));
#pragma unroll
      for (int db = 0; db < 8; db++) {
        int d = db * 16 + li;
        int vpos = (ks * 32 + lg * 8) ^ ((d & 7) << 3);
        bf16x8 vf = __builtin_bit_cast(bf16x8, *(const u32x4*)(Vl + d * 64 + vpos));
        oacc[db] = __builtin_amdgcn_mfma_f32_16x16x32_bf16(pf, vf, oacc[db], 0, 0, 0);
      }
    }
  }

#pragma unroll
  for (int r = 0; r < 4; r++) {
    float inv = 1.0f / lr[r];
    int qrow = qb * 64 + w * 16 + lg * 4 + r;
#pragma unroll
    for (int db = 0; db < 8; db++)
      attnout[(size_t)qrow * HID + h * HD + db * 16 + li] = f2bf(oacc[db][r] * inv);
  }
}

extern "C" void kernel_launch(void* const* d_in, const int* in_sizes, int n_in,
                              void* d_out, int out_size, void* d_ws, size_t ws_size,
                              hipStream_t stream) {
  const float* hidden = (const float*)d_in[0];
  const float* cosb = (const float*)d_in[1];
  const float* sinb = (const float*)d_in[2];
  const float* wqkv = (const float*)d_in[3];
  const float* bqkv = (const float*)d_in[4];
  const float* wo = (const float*)d_in[5];

  char* ws = (char*)d_ws;
  const size_t SZ_HBF = (size_t)SEQ * HID * 2;          // 14,680,064
  const size_t SZ_WQKVT = (size_t)QKVN * HID * 2;       // 33,030,144
  const size_t SZ_QKV = (size_t)SEQ * QKVN * 2;         // 18,874,368
  const size_t SZ_VT = (size_t)NKVH * HD * SEQ * 2;     // 2,097,152
  unsigned short* hbf = (unsigned short*)ws;
  unsigned short* wqkvT = (unsigned short*)(ws + SZ_HBF);
  unsigned short* qkv = (unsigned short*)(ws + SZ_HBF + SZ_WQKVT);
  unsigned short* vt = (unsigned short*)(ws + SZ_HBF + SZ_WQKVT + SZ_QKV);
  unsigned short* attn = (unsigned short*)(ws + SZ_HBF + SZ_WQKVT + SZ_QKV + SZ_VT);
  unsigned short* woT = wqkvT;  // reuse after QKV GEMM consumed wqkvT

  k_cast8<<<dim3(SEQ * HID / 8 / 256), 256, 0, stream>>>(hidden, hbf, SEQ * HID / 8);
  k_tcast<<<dim3(HID / 64, QKVN / 64), 256, 0, stream>>>(wqkv, wqkvT, HID, QKVN);
  k_gemm_bt<<<dim3(SEQ / 128, QKVN / 128), 256, 0, stream>>>(hbf, wqkvT, bqkv, qkv, SEQ, QKVN, HID, 0);
  k_rope<<<dim3(SEQ * 32 * 16 / 256), 256, 0, stream>>>(qkv, cosb, sinb);
  k_vtrans<<<dim3(SEQ / 64, (NKVH * HD) / 64), 256, 0, stream>>>(qkv, vt);
  k_tcast<<<dim3(HID / 64, HID / 64), 256, 0, stream>>>(wo, woT, HID, HID);
  k_attn<<<dim3(SEQ / 64, NQH), 256, 0, stream>>>(qkv, vt, attn);
  k_gemm_bt<<<dim3(SEQ / 128, HID / 128), 256, 0, stream>>>(attn, woT, nullptr, d_out, SEQ, HID, HID, 1);
}

// Round 3
// 328.924 us; speedup vs baseline: 1.0858x; 1.0683x over previous
//
#include <hip/hip_runtime.h>
#include <hip/hip_bf16.h>

#define SEQ 2048
#define HID 3584
#define NQH 28
#define NKVH 4
#define HD 128
#define QKVN 4608
#define WIN 1024

typedef __bf16 bf16x8 __attribute__((ext_vector_type(8)));
typedef float f32x4 __attribute__((ext_vector_type(4)));
typedef unsigned int u32x4 __attribute__((ext_vector_type(4)));
typedef unsigned short u16x4 __attribute__((ext_vector_type(4)));

static __device__ __forceinline__ unsigned short f2bf(float f) {
  unsigned int u = __builtin_bit_cast(unsigned int, f);
  u += 0x7fffu + ((u >> 16) & 1u);
  return (unsigned short)(u >> 16);
}
static __device__ __forceinline__ float bf2f(unsigned short h) {
  unsigned int u = ((unsigned int)h) << 16;
  return __builtin_bit_cast(float, u);
}

// async global->LDS, 16B per lane. lds base must be wave-uniform; HW adds lane*16.
static __device__ __forceinline__ void gload16(const unsigned short* g, unsigned short* l) {
  __builtin_amdgcn_global_load_lds(
      (const __attribute__((address_space(1))) unsigned int*)g,
      (__attribute__((address_space(3))) unsigned int*)l, 16, 0, 0);
}

// ---------- cast f32 -> bf16, 8 elems/thread ----------
__global__ __launch_bounds__(256) void k_cast8(const float* __restrict__ in,
                                               unsigned short* __restrict__ out, int n8) {
  int i = blockIdx.x * 256 + threadIdx.x;
  if (i >= n8) return;
  f32x4 a = ((const f32x4*)in)[2 * i];
  f32x4 b = ((const f32x4*)in)[2 * i + 1];
  union { unsigned short s[8]; u32x4 v; } u;
#pragma unroll
  for (int j = 0; j < 4; j++) { u.s[j] = f2bf(a[j]); u.s[4 + j] = f2bf(b[j]); }
  ((u32x4*)out)[i] = u.v;
}

// ---------- transpose + cast: out[c][r] = bf16(in[r][c]), R,C multiples of 64 ----------
__global__ __launch_bounds__(256) void k_tcast(const float* __restrict__ in,
                                               unsigned short* __restrict__ out, int R, int C) {
  __shared__ unsigned short tile[64][66];
  const int r0 = blockIdx.x * 64, c0 = blockIdx.y * 64;
  const int t = threadIdx.x;
  const int rg = t >> 4, cg = t & 15;
#pragma unroll
  for (int i = 0; i < 4; i++) {
    int rl = rg + i * 16;
    f32x4 v = *(const f32x4*)(in + (size_t)(r0 + rl) * C + c0 + cg * 4);
#pragma unroll
    for (int j = 0; j < 4; j++) tile[rl][cg * 4 + j] = f2bf(v[j]);
  }
  __syncthreads();
#pragma unroll
  for (int i = 0; i < 4; i++) {
    int cl = rg + i * 16;
    u16x4 o;
#pragma unroll
    for (int j = 0; j < 4; j++) o[j] = tile[cg * 4 + j][cl];
    *(u16x4*)(out + (size_t)(c0 + cl) * R + r0 + cg * 4) = o;
  }
}

// ---------- V transpose (bf16): vt[g*128+d][s] = qkv[s][4096 + g*128 + d] ----------
__global__ __launch_bounds__(256) void k_vtrans(const unsigned short* __restrict__ qkv,
                                                unsigned short* __restrict__ vt) {
  __shared__ unsigned short tile[64][66];
  const int r0 = blockIdx.x * 64;  // seq
  const int c0 = blockIdx.y * 64;  // g*128+d in [0,512)
  const int t = threadIdx.x;
  const int rg = t >> 4, cg = t & 15;
#pragma unroll
  for (int i = 0; i < 4; i++) {
    int rl = rg + i * 16;
    u16x4 v = *(const u16x4*)(qkv + (size_t)(r0 + rl) * QKVN + (NQH + NKVH) * HD + c0 + cg * 4);
#pragma unroll
    for (int j = 0; j < 4; j++) tile[rl][cg * 4 + j] = v[j];
  }
  __syncthreads();
#pragma unroll
  for (int i = 0; i < 4; i++) {
    int cl = rg + i * 16;
    u16x4 o;
#pragma unroll
    for (int j = 0; j < 4; j++) o[j] = tile[cg * 4 + j][cl];
    *(u16x4*)(vt + (size_t)(c0 + cl) * SEQ + r0 + cg * 4) = o;
  }
}

// ---------- RoPE in-place on q (heads 0..27) and k (heads 28..31) ----------
__global__ __launch_bounds__(256) void k_rope(unsigned short* __restrict__ qkv,
                                              const float* __restrict__ cosb,
                                              const float* __restrict__ sinb) {
  int idx = blockIdx.x * 256 + threadIdx.x;  // 2048*32*16 total
  int d4 = idx & 15;
  int head = (idx >> 4) & 31;
  int s = idx >> 9;
  unsigned short* row = qkv + (size_t)s * QKVN + head * HD;  // heads 0..31 are contiguous
  int d = d4 * 4;
  u16x4 x1v = *(u16x4*)(row + d);
  u16x4 x2v = *(u16x4*)(row + 64 + d);
  f32x4 c1 = *(const f32x4*)(cosb + s * HD + d);
  f32x4 s1 = *(const f32x4*)(sinb + s * HD + d);
  f32x4 c2 = *(const f32x4*)(cosb + s * HD + 64 + d);
  f32x4 s2 = *(const f32x4*)(sinb + s * HD + 64 + d);
  u16x4 o1, o2;
#pragma unroll
  for (int j = 0; j < 4; j++) {
    float x1 = bf2f(x1v[j]), x2 = bf2f(x2v[j]);
    o1[j] = f2bf(x1 * c1[j] - x2 * s1[j]);
    o2[j] = f2bf(x2 * c2[j] + x1 * s2[j]);
  }
  *(u16x4*)(row + d) = o1;
  *(u16x4*)(row + 64 + d) = o2;
}

// ---------- GEMM C[M][N] = A[M][K] * Bt[N][K]^T ; 128x128 tile, BK=64 ----------
// Double-buffered LDS, 1-deep tile prefetch via global_load_lds with counted
// vmcnt(8) (loads for tile t+1 stay in flight across compute of tile t).
// Raw s_barrier (NOT __syncthreads) so the compiler doesn't drain vmcnt to 0.
// XCD-chunked block swizzle (bijective, m204) for B-panel L2 locality.
// mode 0: C = bf16(A*B + bias)   mode 1: C = f32(A*B)
__global__ __launch_bounds__(256) void k_gemm_bt(const unsigned short* __restrict__ A,
                                                 const unsigned short* __restrict__ Bt,
                                                 const float* __restrict__ bias,
                                                 void* __restrict__ Cout,
                                                 int M, int N, int K, int mode) {
  __shared__ unsigned short Al[2][128 * 64];
  __shared__ unsigned short Bl[2][128 * 64];

  const int gx = gridDim.x;
  const int nwg = gx * gridDim.y;
  const int lin = blockIdx.y * gx + blockIdx.x;
  const int qq = nwg >> 3, rr = nwg & 7;
  const int xcd = lin & 7, idx = lin >> 3;
  const int wg = (xcd < rr ? xcd * (qq + 1) : rr * (qq + 1) + (xcd - rr) * qq) + idx;
  const int m0 = (wg % gx) * 128, n0 = (wg / gx) * 128;

  const int t = threadIdx.x;
  const int w = t >> 6, l = t & 63, lg = l >> 4, li = l & 15;
  const int wr = w >> 1, wc = w & 1;
  f32x4 acc[4][4] = {};
  const int nk = K >> 6;

  // per-lane staging geometry (16B slots). sbase is wave-uniform.
  const int sb0 = w * 64;
  const int srow0 = (sb0 + l) >> 3;        // rows covered: advance by 32 per i
  const int ssl = (sb0 + l) & 7;

  // prologue: stage tile 0 into buf 0
#pragma unroll
  for (int i = 0; i < 4; i++) {
    int sbase = i * 256 + sb0;
    int row = srow0 + i * 32;
    int slsrc = ssl ^ (row & 7);
    gload16(A + (size_t)(m0 + row) * K + slsrc * 8, Al[0] + sbase * 8);
    gload16(Bt + (size_t)(n0 + row) * K + slsrc * 8, Bl[0] + sbase * 8);
  }

  for (int kt = 0; kt < nk; kt++) {
    const int buf = kt & 1;
    if (kt + 1 < nk) {
      // prefetch tile kt+1 into the other buffer
#pragma unroll
      for (int i = 0; i < 4; i++) {
        int sbase = i * 256 + sb0;
        int row = srow0 + i * 32;
        int slsrc = ssl ^ (row & 7);
        gload16(A + (size_t)(m0 + row) * K + (kt + 1) * 64 + slsrc * 8, Al[buf ^ 1] + sbase * 8);
        gload16(Bt + (size_t)(n0 + row) * K + (kt + 1) * 64 + slsrc * 8, Bl[buf ^ 1] + sbase * 8);
      }
      asm volatile("s_waitcnt vmcnt(8)" ::: "memory");  // tile kt's 8 loads done; 8 in flight
    } else {
      asm volatile("s_waitcnt vmcnt(0)" ::: "memory");
    }
    __builtin_amdgcn_s_barrier();

    const unsigned short* Ab = Al[buf];
    const unsigned short* Bb = Bl[buf];
#pragma unroll
    for (int ks = 0; ks < 2; ks++) {
      bf16x8 af[4], bfr[4];
#pragma unroll
      for (int mi = 0; mi < 4; mi++) {
        int row = wr * 64 + mi * 16 + li;
        af[mi] = __builtin_bit_cast(
            bf16x8, *(const u32x4*)(Ab + row * 64 + ((ks * 32 + lg * 8) ^ ((row & 7) << 3))));
      }
#pragma unroll
      for (int ni = 0; ni < 4; ni++) {
        int row = wc * 64 + ni * 16 + li;
        bfr[ni] = __builtin_bit_cast(
            bf16x8, *(const u32x4*)(Bb + row * 64 + ((ks * 32 + lg * 8) ^ ((row & 7) << 3))));
      }
#pragma unroll
      for (int mi = 0; mi < 4; mi++)
#pragma unroll
        for (int ni = 0; ni < 4; ni++)
          acc[mi][ni] = __builtin_amdgcn_mfma_f32_16x16x32_bf16(af[mi], bfr[ni], acc[mi][ni], 0, 0, 0);
    }
    __builtin_amdgcn_s_barrier();
  }

  if (mode == 0) {
    float bv[4];
#pragma unroll
    for (int ni = 0; ni < 4; ni++) bv[ni] = bias[n0 + wc * 64 + ni * 16 + li];
    unsigned short* C16 = (unsigned short*)Cout;
#pragma unroll
    for (int mi = 0; mi < 4; mi++)
#pragma unroll
      for (int ni = 0; ni < 4; ni++)
#pragma unroll
        for (int r = 0; r < 4; r++) {
          int m = m0 + wr * 64 + mi * 16 + lg * 4 + r;
          int n = n0 + wc * 64 + ni * 16 + li;
          C16[(size_t)m * N + n] = f2bf(acc[mi][ni][r] + bv[ni]);
        }
  } else {
    float* Cf = (float*)Cout;
#pragma unroll
    for (int mi = 0; mi < 4; mi++)
#pragma unroll
      for (int ni = 0; ni < 4; ni++)
#pragma unroll
        for (int r = 0; r < 4; r++) {
          int m = m0 + wr * 64 + mi * 16 + lg * 4 + r;
          int n = n0 + wc * 64 + ni * 16 + li;
          Cf[(size_t)m * N + n] = acc[mi][ni][r];
        }
  }
}

// ---------- flash attention, sliding window, GQA ----------
// block = (qb, h): 64 q rows, head h (kv group h/7). 4 waves x 16 rows.
__global__ __launch_bounds__(256) void k_attn(const unsigned short* __restrict__ qkv,
                                              const unsigned short* __restrict__ vt,
                                              unsigned short* __restrict__ attnout) {
  __shared__ unsigned short Kl[64 * 128];
  __shared__ unsigned short Vl[128 * 64];
  __shared__ unsigned short Pl[4][16 * 64];

  const int qb = blockIdx.x;
  const int h = blockIdx.y;
  const int g = h / 7;
  const int t = threadIdx.x;
  const int w = t >> 6, l = t & 63, lg = l >> 4, li = l & 15;

  bf16x8 qf[4];
  {
    const int qrow = qb * 64 + w * 16 + li;
    const unsigned short* qp = qkv + (size_t)qrow * QKVN + h * HD;
#pragma unroll
    for (int ks = 0; ks < 4; ks++)
      qf[ks] = __builtin_bit_cast(bf16x8, *(const u32x4*)(qp + ks * 32 + lg * 8));
  }

  f32x4 oacc[8] = {};
  float mr[4], lr[4];
#pragma unroll
  for (int r = 0; r < 4; r++) { mr[r] = -1e30f; lr[r] = 0.f; }

  const int kt_lo = qb >= 16 ? qb - 16 : 0;
  const float scale = 0.088388347648318447f;  // 1/sqrt(128)

  for (int kt = kt_lo; kt <= qb; kt++) {
    __syncthreads();
    // stage K tile [64 keys][128 d], swizzled
#pragma unroll
    for (int i = 0; i < 4; i++) {
      int s = t + i * 256;
      int row = s >> 4, sl = s & 15;
      u32x4 v = *(const u32x4*)(qkv + (size_t)(kt * 64 + row) * QKVN + NQH * HD + g * HD + sl * 8);
      *(u32x4*)(Kl + row * 128 + ((sl ^ (row & 7)) * 8)) = v;
    }
    // stage V^T tile [128 d][64 keys], swizzled
#pragma unroll
    for (int i = 0; i < 4; i++) {
      int s = t + i * 256;
      int row = s >> 3, sl = s & 7;  // row = d
      u32x4 v = *(const u32x4*)(vt + (size_t)(g * HD + row) * SEQ + kt * 64 + sl * 8);
      *(u32x4*)(Vl + row * 64 + ((sl ^ (row & 7)) * 8)) = v;
    }
    __syncthreads();

    // S = Q K^T
    f32x4 sc[4] = {};
#pragma unroll
    for (int ks = 0; ks < 4; ks++) {
#pragma unroll
      for (int kb = 0; kb < 4; kb++) {
        int key = kb * 16 + li;
        int pos = (ks * 32 + lg * 8) ^ ((key & 7) << 3);
        bf16x8 kf = __builtin_bit_cast(bf16x8, *(const u32x4*)(Kl + key * 128 + pos));
        sc[kb] = __builtin_amdgcn_mfma_f32_16x16x32_bf16(qf[ks], kf, sc[kb], 0, 0, 0);
      }
    }

    // online softmax (rows partition by 16-lane group; reg r = row lg*4+r)
    float alpha[4];
#pragma unroll
    for (int r = 0; r < 4; r++) {
      int qg = qb * 64 + w * 16 + lg * 4 + r;
      float sv[4];
      float mx = -1e30f;
#pragma unroll
      for (int kb = 0; kb < 4; kb++) {
        int kg = kt * 64 + kb * 16 + li;
        float x = sc[kb][r] * scale;
        bool ok = (kg <= qg) && (qg - kg < WIN);
        sv[kb] = ok ? x : -1e30f;
        mx = fmaxf(mx, sv[kb]);
      }
#pragma unroll
      for (int off = 1; off < 16; off <<= 1) mx = fmaxf(mx, __shfl_xor(mx, off));
      float mn = fmaxf(mr[r], mx);
      alpha[r] = __expf(mr[r] - mn);
      float rs = 0.f;
      int q_l = lg * 4 + r;
#pragma unroll
      for (int kb = 0; kb < 4; kb++) {
        float p = (sv[kb] > -1e29f) ? __expf(sv[kb] - mn) : 0.f;
        rs += p;
        Pl[w][q_l * 64 + (((kb * 16 + li) ^ ((q_l & 7) << 3)))] = f2bf(p);
      }
#pragma unroll
      for (int off = 1; off < 16; off <<= 1) rs += __shfl_xor(rs, off);
      lr[r] = lr[r] * alpha[r] + rs;
      mr[r] = mn;
    }
#pragma unroll
    for (int db = 0; db < 8; db++)
#pragma unroll
      for (int r = 0; r < 4; r++) oacc[db][r] *= alpha[r];
    __syncthreads();  // P visible for A-fragment reads

    // O += P V
#pragma unroll
    for (int ks = 0; ks < 2; ks++) {
      int ppos = (ks * 32 + lg * 8) ^ ((li & 7) << 3);
      bf16x8 pf = __builtin_bit_cast(bf16x8, *(const u32x4*)(&Pl[w][li * 64 + ppos]));
#pragma unroll
      for (int db = 0; db < 8; db++) {
        int d = db * 16 + li;
        int vpos = (ks * 32 + lg * 8) ^ ((d & 7) << 3);
        bf16x8 vf = __builtin_bit_cast(bf16x8, *(const u32x4*)(Vl + d * 64 + vpos));
        oacc[db] = __builtin_amdgcn_mfma_f32_16x16x32_bf16(pf, vf, oacc[db], 0, 0, 0);
      }
    }
  }

#pragma unroll
  for (int r = 0; r < 4; r++) {
    float inv = 1.0f / lr[r];
    int qrow = qb * 64 + w * 16 + lg * 4 + r;
#pragma unroll
    for (int db = 0; db < 8; db++)
      attnout[(size_t)qrow * HID + h * HD + db * 16 + li] = f2bf(oacc[db][r] * inv);
  }
}

extern "C" void kernel_launch(void* const* d_in, const int* in_sizes, int n_in,
                              void* d_out, int out_size, void* d_ws, size_t ws_size,
                              hipStream_t stream) {
  const float* hidden = (const float*)d_in[0];
  const float* cosb = (const float*)d_in[1];
  const float* sinb = (const float*)d_in[2];
  const float* wqkv = (const float*)d_in[3];
  const float* bqkv = (const float*)d_in[4];
  const float* wo = (const float*)d_in[5];

  char* ws = (char*)d_ws;
  const size_t SZ_HBF = (size_t)SEQ * HID * 2;          // 14,680,064
  const size_t SZ_WQKVT = (size_t)QKVN * HID * 2;       // 33,030,144
  const size_t SZ_QKV = (size_t)SEQ * QKVN * 2;         // 18,874,368
  const size_t SZ_VT = (size_t)NKVH * HD * SEQ * 2;     // 2,097,152
  unsigned short* hbf = (unsigned short*)ws;
  unsigned short* wqkvT = (unsigned short*)(ws + SZ_HBF);
  unsigned short* qkv = (unsigned short*)(ws + SZ_HBF + SZ_WQKVT);
  unsigned short* vt = (unsigned short*)(ws + SZ_HBF + SZ_WQKVT + SZ_QKV);
  unsigned short* attn = (unsigned short*)(ws + SZ_HBF + SZ_WQKVT + SZ_QKV + SZ_VT);
  unsigned short* woT = wqkvT;  // reuse after QKV GEMM consumed wqkvT

  k_cast8<<<dim3(SEQ * HID / 8 / 256), 256, 0, stream>>>(hidden, hbf, SEQ * HID / 8);
  k_tcast<<<dim3(HID / 64, QKVN / 64), 256, 0, stream>>>(wqkv, wqkvT, HID, QKVN);
  k_gemm_bt<<<dim3(SEQ / 128, QKVN / 128), 256, 0, stream>>>(hbf, wqkvT, bqkv, qkv, SEQ, QKVN, HID, 0);
  k_rope<<<dim3(SEQ * 32 * 16 / 256), 256, 0, stream>>>(qkv, cosb, sinb);
  k_vtrans<<<dim3(SEQ / 64, (NKVH * HD) / 64), 256, 0, stream>>>(qkv, vt);
  k_tcast<<<dim3(HID / 64, HID / 64), 256, 0, stream>>>(wo, woT, HID, HID);
  k_attn<<<dim3(SEQ / 64, NQH), 256, 0, stream>>>(qkv, vt, attn);
  k_gemm_bt<<<dim3(SEQ / 128, HID / 128), 256, 0, stream>>>(attn, woT, nullptr, d_out, SEQ, HID, HID, 1);
}